// Round 6
// baseline (409.887 us; speedup 1.0000x reference)
//
#include <hip/hip_runtime.h>

#define DF 64       // feature dim
#define WSTRIDE 132 // LDS row stride for W (mult of 4 keeps 16B align; %32==4 spreads banks)
#define ELLK 48     // ELL width; max degree ~36 for E/N=16 multinomial at N=1e5

__device__ __forceinline__ unsigned short bf16rne(float f) {
    unsigned u = __float_as_uint(f);
    unsigned r = u + 0x7fffu + ((u >> 16) & 1u);  // round-to-nearest-even
    return (unsigned short)(r >> 16);
}
__device__ __forceinline__ float b2f(unsigned short u) {
    return __uint_as_float((unsigned)u << 16);
}

// ---------------------------------------------------------------------------
// Kernel A: h (fp32) -> hb (bf16), and zero the degree/overflow counters
// (folded here to save a memset dispatch; each gap costs ~25 us).
// ---------------------------------------------------------------------------
__global__ __launch_bounds__(256) void conv_zero(
    const float* __restrict__ h, unsigned short* __restrict__ hb,
    int* __restrict__ cnt, int total4, int nzero)
{
    int gid = blockIdx.x * 256 + threadIdx.x;
    if (gid < nzero) cnt[gid] = 0;
    int i = gid * 4;
    if (i + 3 < total4 * 4) {
        float4 v = *(const float4*)&h[i];
        ushort4 o;
        o.x = bf16rne(v.x); o.y = bf16rne(v.y);
        o.z = bf16rne(v.z); o.w = bf16rne(v.w);
        *(ushort4*)&hb[i] = o;
    }
}

// ---------------------------------------------------------------------------
// Kernel B: one-pass ELL build. slot = atomicAdd(cnt[dst]); the src store
// uses atomicExch, NOT a plain store: scattered 4B plain stores amplify to
// 64B sectors (~100 MB measured r3), atomics write through at ~4B (r1).
// Overflow (slot >= ELLK) -> (dst,src) list, exact slow path in kernel C.
// ---------------------------------------------------------------------------
__device__ __forceinline__ void ell_push(
    int d, int s, int* cnt, int* ell, int* ovf, int* ovfcnt, int cap)
{
    int slot = atomicAdd(&cnt[d], 1);
    if (slot < ELLK) {
        atomicExch(&ell[(size_t)d * ELLK + slot], s);  // 4B write-through
    } else {
        int p = atomicAdd(ovfcnt, 1);
        if (p < cap) { atomicExch(&ovf[2 * p], d); atomicExch(&ovf[2 * p + 1], s); }
    }
}

__global__ __launch_bounds__(256) void fill_ell(
    const int* __restrict__ src, const int* __restrict__ dst,
    int* __restrict__ cnt, int* __restrict__ ell,
    int* __restrict__ ovf, int* __restrict__ ovfcnt, int ovfcap, int E)
{
    int i = (blockIdx.x * 256 + threadIdx.x) * 4;
    if (i + 3 < E) {
        int4 d = *(const int4*)&dst[i];
        int4 s = *(const int4*)&src[i];
        ell_push(d.x, s.x, cnt, ell, ovf, ovfcnt, ovfcap);
        ell_push(d.y, s.y, cnt, ell, ovf, ovfcnt, ovfcap);
        ell_push(d.z, s.z, cnt, ell, ovf, ovfcnt, ovfcap);
        ell_push(d.w, s.w, cnt, ell, ovf, ovfcnt, ovfcap);
    } else {
        for (; i < E; ++i) ell_push(dst[i], src[i], cnt, ell, ovf, ovfcnt, ovfcap);
    }
}

// ---------------------------------------------------------------------------
// Kernel C: fused gather + update. One wave per node; 8 waves/block share
// one LDS copy of W. ALL feature reads come from bf16 hb (12.8 MB):
//  - gather rows (random): cached, per-XCD compulsory ~12.8 MB x 8
//  - own row hv: 1 line, usually warm from gather traffic
// ELL rows are read nontemporal and out is written nontemporal so the
// streaming traffic doesn't evict hb from the 4 MB per-XCD L2.
// Epilogue (verified r1-r5): LDS-staged x, W-row dot, L2-normalize, relu,
// where(deg>0), residual.
// ---------------------------------------------------------------------------
__global__ __launch_bounds__(512, 4) void sage_fused(
    const unsigned short* __restrict__ hb,
    const float* __restrict__ W, const float* __restrict__ b,
    const int* __restrict__ cnt, const int* __restrict__ ell,
    const int* __restrict__ ovf, const int* __restrict__ ovfcnt,
    int ovfcap, float* __restrict__ out, int N)
{
    __shared__ float Wp[DF * WSTRIDE];   // ~33 KB
    __shared__ float bs[DF];
    __shared__ float xbuf[8][128];

    for (int i = threadIdx.x; i < DF * 128; i += 512) {
        int o = i >> 7, k = i & 127;
        Wp[o * WSTRIDE + k] = W[i];
    }
    if (threadIdx.x < DF) bs[threadIdx.x] = b[threadIdx.x];
    __syncthreads();

    const int wave = threadIdx.x >> 6;
    const int lane = threadIdx.x & 63;
    const int g    = lane >> 4;        // neighbor sub-slot 0..3
    const int fo   = (lane & 15) * 4;  // 4-feature offset within a row
    const int gw = blockIdx.x * 8 + wave;
    const int nw = gridDim.x * 8;
    float* xb = xbuf[wave];
    const float* wrow = &Wp[lane * WSTRIDE];
    const float bias = bs[lane];

    for (int n = gw; n < N; n += nw) {
        int deg = cnt[n];
        int m = deg < ELLK ? deg : ELLK;
        float hv = b2f(hb[(size_t)n * DF + lane]);  // own row, 1 line, warm

        int idx = (lane < m)
            ? __builtin_nontemporal_load(&ell[(size_t)n * ELLK + lane]) : 0;

        float4 a0 = make_float4(0.f, 0.f, 0.f, 0.f);
        float4 a1 = make_float4(0.f, 0.f, 0.f, 0.f);
        float4 a2 = make_float4(0.f, 0.f, 0.f, 0.f);
        float4 a3 = make_float4(0.f, 0.f, 0.f, 0.f);
        for (int j = 0; j < m; j += 16) {
            int i0 = j + g, i1 = j + g + 4, i2 = j + g + 8, i3 = j + g + 12;
            int id0 = __shfl(idx, i0 & 63);
            int id1 = __shfl(idx, i1 & 63);
            int id2 = __shfl(idx, i2 & 63);
            int id3 = __shfl(idx, i3 & 63);
            if (i0 < m) {
                ushort4 u = *(const ushort4*)&hb[(size_t)id0 * DF + fo];
                a0.x += b2f(u.x); a0.y += b2f(u.y); a0.z += b2f(u.z); a0.w += b2f(u.w);
            }
            if (i1 < m) {
                ushort4 u = *(const ushort4*)&hb[(size_t)id1 * DF + fo];
                a1.x += b2f(u.x); a1.y += b2f(u.y); a1.z += b2f(u.z); a1.w += b2f(u.w);
            }
            if (i2 < m) {
                ushort4 u = *(const ushort4*)&hb[(size_t)id2 * DF + fo];
                a2.x += b2f(u.x); a2.y += b2f(u.y); a2.z += b2f(u.z); a2.w += b2f(u.w);
            }
            if (i3 < m) {
                ushort4 u = *(const ushort4*)&hb[(size_t)id3 * DF + fo];
                a3.x += b2f(u.x); a3.y += b2f(u.y); a3.z += b2f(u.z); a3.w += b2f(u.w);
            }
        }
        a0.x += a1.x + a2.x + a3.x;
        a0.y += a1.y + a2.y + a3.y;
        a0.z += a1.z + a2.z + a3.z;
        a0.w += a1.w + a2.w + a3.w;
        #pragma unroll
        for (int s = 16; s < 64; s <<= 1) {
            a0.x += __shfl_xor(a0.x, s);
            a0.y += __shfl_xor(a0.y, s);
            a0.z += __shfl_xor(a0.z, s);
            a0.w += __shfl_xor(a0.w, s);
        }

        // overflow slow path (deg > ELLK): scan (dst,src) list
        float extra = 0.f;
        if (deg > ELLK) {
            int oc = *ovfcnt; if (oc > ovfcap) oc = ovfcap;
            for (int t = 0; t < oc; ++t) {
                int d2 = ovf[2 * t];
                if (d2 == n) extra += b2f(hb[(size_t)ovf[2 * t + 1] * DF + lane]);
            }
        }

        float dg = (float)deg;
        float inv = 1.0f / fmaxf(dg, 1.0f);

        // stage x = [h, c] in per-wave LDS (wave-synchronous, no barrier)
        if (g == 0) *(float4*)&xb[DF + fo] = a0;  // raw sums, lanes 0..15
        xb[lane] = hv;
        float cv = (xb[DF + lane] + extra) * inv;
        xb[DF + lane] = cv;

        // y = [h,c]·W^T + b
        float y = bias;
        #pragma unroll
        for (int k = 0; k < 128; k += 4) {
            float4 xk = *(const float4*)&xb[k];    // same-address broadcast
            float4 wk = *(const float4*)&wrow[k];
            y += xk.x * wk.x;
            y += xk.y * wk.y;
            y += xk.z * wk.z;
            y += xk.w * wk.w;
        }

        // L2 norm across 64 lanes
        float ss = y * y;
        #pragma unroll
        for (int s = 1; s < 64; s <<= 1) ss += __shfl_xor(ss, s);

        float norm = sqrtf(ss);
        float nb2 = y / fmaxf(norm, 1e-12f);
        float nh = fmaxf(nb2, 0.0f);
        float hupd = (dg > 0.0f) ? nh : hv;
        __builtin_nontemporal_store(hv + hupd, &out[(size_t)n * DF + lane]);
    }
}

extern "C" void kernel_launch(void* const* d_in, const int* in_sizes, int n_in,
                              void* d_out, int out_size, void* d_ws, size_t ws_size,
                              hipStream_t stream) {
    const float* h   = (const float*)d_in[0];
    const float* W   = (const float*)d_in[1];
    const float* b   = (const float*)d_in[2];
    const int*   src = (const int*)d_in[3];
    const int*   dst = (const int*)d_in[4];
    float* out = (float*)d_out;

    const int N = in_sizes[0] / DF;
    const int E = in_sizes[3];

    // workspace carve (16B-aligned sections)
    int* cnt    = (int*)d_ws;                       // N + pad; ovfcnt = cnt+N
    int* ovfcnt = cnt + N;
    int* ell    = cnt + ((N + 31) & ~15);           // N * ELLK
    unsigned short* hb = (unsigned short*)(ell + (((size_t)N * ELLK + 15) & ~(size_t)15));
    int* ovf    = (int*)(hb + (((size_t)N * DF + 15) & ~(size_t)15));
    size_t used = (size_t)((char*)ovf - (char*)d_ws);
    int ovfcap  = (ws_size > used + 64) ? (int)((ws_size - used) / 8 - 4) : 0;

    const int total4 = (N * DF) / 4;       // N*DF divisible by 4
    const int nzero  = N + 16;             // cnt region incl. ovfcnt

    // A: bf16 conversion + counter zeroing (1.6M threads covers nzero)
    conv_zero<<<(total4 + 255) / 256, 256, 0, stream>>>(h, hb, cnt, total4, nzero);

    // B: one-pass ELL build (atomic stores: no 64B sector amplification)
    fill_ell<<<(E / 4 + 255) / 256, 256, 0, stream>>>(
        src, dst, cnt, ell, ovf, ovfcnt, ovfcap, E);

    // C: fused gather + update
    sage_fused<<<2048, 512, 0, stream>>>(
        hb, W, b, cnt, ell, ovf, ovfcnt, ovfcap, out, N);
}

// Round 7
// 404.360 us; speedup vs baseline: 1.0137x; 1.0137x over previous
//
#include <hip/hip_runtime.h>

#define DF 64
#define WSTRIDE 132 // LDS row stride for W (mult of 4 keeps 16B align; %32==4 spreads banks)
#define ELLK 32     // Poisson(16): P(deg>32)~1e-4 -> ovf list handles stragglers exactly

__device__ __forceinline__ unsigned short bf16rne(float f) {
    unsigned u = __float_as_uint(f);
    unsigned r = u + 0x7fffu + ((u >> 16) & 1u);
    return (unsigned short)(r >> 16);
}
__device__ __forceinline__ float b2f(unsigned short u) {
    return __uint_as_float((unsigned)u << 16);
}

// ---------------------------------------------------------------------------
// K1: h (fp32) -> hbs in SLICE-MAJOR bf16 layout (slice s = feats [8s,8s+8),
// sub-table s is N*16B = 1.6 MB -> fits one XCD's 4 MB L2). Also zeroes
// cnt/ovfcnt (folded to save a dispatch).
// ---------------------------------------------------------------------------
__global__ __launch_bounds__(256) void conv_zero(
    const float* __restrict__ h, unsigned short* __restrict__ hbs,
    int* __restrict__ cnt, int N)
{
    int tid = blockIdx.x * 256 + threadIdx.x;
    if (tid < N + 16) cnt[tid] = 0;
    if (tid < N * 8) {
        int n = tid >> 3, s = tid & 7;
        const float* hp = &h[(size_t)n * DF + s * 8];
        float4 v0 = *(const float4*)hp;
        float4 v1 = *(const float4*)(hp + 4);
        ushort4 o0, o1;
        o0.x = bf16rne(v0.x); o0.y = bf16rne(v0.y); o0.z = bf16rne(v0.z); o0.w = bf16rne(v0.w);
        o1.x = bf16rne(v1.x); o1.y = bf16rne(v1.y); o1.z = bf16rne(v1.z); o1.w = bf16rne(v1.w);
        unsigned short* op = &hbs[(size_t)s * N * 8 + (size_t)n * 8];
        *(ushort4*)op = o0;
        *(ushort4*)(op + 4) = o1;
    }
}

// ---------------------------------------------------------------------------
// K2: dst-partitioned ELL fill. Block's partition p = blockIdx&7 (-> XCD via
// round-robin dispatch heuristic; correctness never depends on the mapping).
// Each partition streams ALL edges but only applies dst in its N/8 range, so
// its cnt slice (50 KB) and ELL slice (1.6 MB) stay L2-resident. Plain
// stores (r6: atomicExch regressed ~30us - atomic pipe RMW serializes).
// ---------------------------------------------------------------------------
__device__ __forceinline__ void ell_push(
    int d, int s, int* cnt, int* ell, int* ovf, int* ovfcnt, int cap)
{
    int slot = atomicAdd(&cnt[d], 1);
    if (slot < ELLK) {
        ell[(size_t)d * ELLK + slot] = s;
    } else {
        int p = atomicAdd(ovfcnt, 1);
        if (p < cap) { ovf[2 * p] = d; ovf[2 * p + 1] = s; }
    }
}

__global__ __launch_bounds__(256) void fill_ell(
    const int* __restrict__ src, const int* __restrict__ dst,
    int* __restrict__ cnt, int* __restrict__ ell,
    int* __restrict__ ovf, int* __restrict__ ovfcnt, int ovfcap, int E, int N)
{
    int part = blockIdx.x & 7;
    int chunk = blockIdx.x >> 3;
    int nchunks = gridDim.x >> 3;
    int lo = (int)((long long)part * N / 8);
    int hi = (int)((long long)(part + 1) * N / 8);
    int seg = ((E + nchunks - 1) / nchunks + 3) & ~3;  // 4-aligned segments
    int e0 = chunk * seg;
    int e1 = e0 + seg; if (e1 > E) e1 = E;

    for (int i = e0 + threadIdx.x * 4; i < e1; i += 256 * 4) {
        if (i + 3 < e1) {
            int4 d = *(const int4*)&dst[i];
            int4 s = *(const int4*)&src[i];
            if (d.x >= lo && d.x < hi) ell_push(d.x, s.x, cnt, ell, ovf, ovfcnt, ovfcap);
            if (d.y >= lo && d.y < hi) ell_push(d.y, s.y, cnt, ell, ovf, ovfcnt, ovfcap);
            if (d.z >= lo && d.z < hi) ell_push(d.z, s.z, cnt, ell, ovf, ovfcnt, ovfcap);
            if (d.w >= lo && d.w < hi) ell_push(d.w, s.w, cnt, ell, ovf, ovfcnt, ovfcap);
        } else {
            for (int j = i; j < e1; ++j) {
                int d = dst[j];
                if (d >= lo && d < hi) ell_push(d, src[j], cnt, ell, ovf, ovfcnt, ovfcap);
            }
        }
    }
}

// ---------------------------------------------------------------------------
// K3: feature-sliced gather. Slice s = blockIdx&7 (-> its XCD); all gathers
// hit the L2-resident 1.6 MB hbs sub-table. One wave per node per slice;
// deg<=ELLK=32 so one pass: lane (g2=lane>>1, fp=lane&1) loads neighbor
// g2's 4-feat ushort4; butterfly over masks {2..32} sums the 32 neighbor
// groups; lanes 0/1 store the 8-feat bf16 partial sum to csum slice.
// ---------------------------------------------------------------------------
__global__ __launch_bounds__(512) void gather_slice(
    const unsigned short* __restrict__ hbs, const int* __restrict__ cnt,
    const int* __restrict__ ell, unsigned short* __restrict__ csum, int N)
{
    int slice = blockIdx.x & 7;
    int wave = threadIdx.x >> 6, lane = threadIdx.x & 63;
    int gw = (blockIdx.x >> 3) * 8 + wave;
    int nw = (gridDim.x >> 3) * 8;
    const unsigned short* tab = hbs + (size_t)slice * N * 8;
    unsigned short* cs = csum + (size_t)slice * N * 8;
    int g2 = lane >> 1, fp = lane & 1;

    for (int n = gw; n < N; n += nw) {
        int deg = cnt[n];
        int m = deg < ELLK ? deg : ELLK;
        int idx = (lane < m) ? ell[(size_t)n * ELLK + lane] : 0;

        float a0 = 0.f, a1 = 0.f, a2 = 0.f, a3 = 0.f;
        if (g2 < m) {
            int id = __shfl(idx, g2);
            ushort4 u = *(const ushort4*)&tab[(size_t)id * 8 + fp * 4];
            a0 = b2f(u.x); a1 = b2f(u.y); a2 = b2f(u.z); a3 = b2f(u.w);
        }
        #pragma unroll
        for (int msk = 2; msk < 64; msk <<= 1) {
            a0 += __shfl_xor(a0, msk);
            a1 += __shfl_xor(a1, msk);
            a2 += __shfl_xor(a2, msk);
            a3 += __shfl_xor(a3, msk);
        }
        if (lane < 2) {
            ushort4 o;
            o.x = bf16rne(a0); o.y = bf16rne(a1);
            o.z = bf16rne(a2); o.w = bf16rne(a3);
            *(ushort4*)&cs[(size_t)n * 8 + fp * 4] = o;  // bf16 partial SUM
        }
    }
}

// ---------------------------------------------------------------------------
// K4: streaming update (verified epilogue r1-r6). One wave per node; 8 waves
// share one LDS W copy. Reads h fp32 (coalesced), assembles c from the 8
// csum slices (adjacent waves cover adjacent nodes -> chunks tile lines),
// then LDS-staged dot / L2-normalize / relu / where(deg>0) / residual.
// ---------------------------------------------------------------------------
__global__ __launch_bounds__(512, 4) void sage_update(
    const float* __restrict__ h, const float* __restrict__ W,
    const float* __restrict__ b, const int* __restrict__ cnt,
    const unsigned short* __restrict__ csum,
    const int* __restrict__ ovf, const int* __restrict__ ovfcnt,
    int ovfcap, float* __restrict__ out, int N)
{
    __shared__ float Wp[DF * WSTRIDE];
    __shared__ float bs[DF];
    __shared__ float xbuf[8][128];

    for (int i = threadIdx.x; i < DF * 128; i += 512) {
        int o = i >> 7, k = i & 127;
        Wp[o * WSTRIDE + k] = W[i];
    }
    if (threadIdx.x < DF) bs[threadIdx.x] = b[threadIdx.x];
    __syncthreads();

    const int wave = threadIdx.x >> 6;
    const int lane = threadIdx.x & 63;
    const int gw = blockIdx.x * 8 + wave;
    const int nw = gridDim.x * 8;
    float* xb = xbuf[wave];
    const float* wrow = &Wp[lane * WSTRIDE];
    const float bias = bs[lane];
    const size_t coff = (size_t)(lane >> 3) * N * 8 + (lane & 7);  // slice-major

    for (int n = gw; n < N; n += nw) {
        int deg = cnt[n];
        float hv = h[(size_t)n * DF + lane];
        float csv = b2f(csum[coff + (size_t)n * 8]);  // my feature's partial sum

        // overflow slow path (deg > ELLK): exact fp32 additions
        if (deg > ELLK) {
            int oc = *ovfcnt; if (oc > ovfcap) oc = ovfcap;
            for (int t = 0; t < oc; ++t) {
                if (ovf[2 * t] == n) csv += h[(size_t)ovf[2 * t + 1] * DF + lane];
            }
        }

        float dg = (float)deg;
        float cv = csv / fmaxf(dg, 1.0f);

        // stage x = [h, c] in per-wave LDS (wave-synchronous)
        xb[lane] = hv;
        xb[DF + lane] = cv;

        float y = bias;
        #pragma unroll
        for (int k = 0; k < 128; k += 4) {
            float4 xk = *(const float4*)&xb[k];
            float4 wk = *(const float4*)&wrow[k];
            y += xk.x * wk.x;
            y += xk.y * wk.y;
            y += xk.z * wk.z;
            y += xk.w * wk.w;
        }

        float ss = y * y;
        #pragma unroll
        for (int s = 1; s < 64; s <<= 1) ss += __shfl_xor(ss, s);

        float norm = sqrtf(ss);
        float nb2 = y / fmaxf(norm, 1e-12f);
        float nh = fmaxf(nb2, 0.0f);
        float hupd = (dg > 0.0f) ? nh : hv;
        out[(size_t)n * DF + lane] = hv + hupd;
    }
}

extern "C" void kernel_launch(void* const* d_in, const int* in_sizes, int n_in,
                              void* d_out, int out_size, void* d_ws, size_t ws_size,
                              hipStream_t stream) {
    const float* h   = (const float*)d_in[0];
    const float* W   = (const float*)d_in[1];
    const float* b   = (const float*)d_in[2];
    const int*   src = (const int*)d_in[3];
    const int*   dst = (const int*)d_in[4];
    float* out = (float*)d_out;

    const int N = in_sizes[0] / DF;
    const int E = in_sizes[3];

    // workspace carve (16B-aligned)
    int* cnt    = (int*)d_ws;                               // N (+16 incl ovfcnt)
    int* ovfcnt = cnt + N;
    int* ell    = cnt + ((N + 31) & ~15);                   // N*ELLK ints (12.8 MB)
    unsigned short* hbs  = (unsigned short*)(ell + (((size_t)N * ELLK + 15) & ~(size_t)15));
    unsigned short* csum = hbs + (((size_t)N * DF + 15) & ~(size_t)15);   // 12.8 MB each
    int* ovf    = (int*)(csum + (((size_t)N * DF + 15) & ~(size_t)15));
    size_t used = (size_t)((char*)ovf - (char*)d_ws);
    int ovfcap  = (ws_size > used + 64) ? (int)((ws_size - used) / 8 - 4) : 0;

    // K1: bf16 slice-major conversion + counter zeroing
    conv_zero<<<(N * 8 + 255) / 256, 256, 0, stream>>>(h, hbs, cnt, N);

    // K2: dst-partitioned ELL build (128 chunks x 8 partitions)
    fill_ell<<<1024, 256, 0, stream>>>(src, dst, cnt, ell, ovf, ovfcnt, ovfcap, E, N);

    // K3: feature-sliced gather (256 blocks per slice x 8 slices)
    gather_slice<<<2048, 512, 0, stream>>>(hbs, cnt, ell, csum, N);

    // K4: streaming update
    sage_update<<<1024, 512, 0, stream>>>(h, W, b, cnt, csum, ovf, ovfcnt, ovfcap, out, N);
}

// Round 8
// 279.216 us; speedup vs baseline: 1.4680x; 1.4482x over previous
//
#include <hip/hip_runtime.h>

#define DF 64
#define WSTRIDE 132 // LDS row stride for W (mult of 4 keeps 16B align; %32==4 spreads banks)
#define ELLK 32     // Poisson(16): P(deg>32)~1e-4 -> ovf list handles stragglers exactly

__device__ __forceinline__ unsigned short bf16rne(float f) {
    unsigned u = __float_as_uint(f);
    unsigned r = u + 0x7fffu + ((u >> 16) & 1u);
    return (unsigned short)(r >> 16);
}
__device__ __forceinline__ float b2f(unsigned short u) {
    return __uint_as_float((unsigned)u << 16);
}

// ---------------------------------------------------------------------------
// K1: h (fp32) -> hbs in SLICE-MAJOR bf16 layout (slice s = feats [8s,8s+8);
// sub-table s is N*16B = 1.6 MB -> fits one XCD's 4 MB L2). Also zeroes
// cnt/ovfcnt (folded to save a dispatch).
// ---------------------------------------------------------------------------
__global__ __launch_bounds__(256) void conv_zero(
    const float* __restrict__ h, unsigned short* __restrict__ hbs,
    int* __restrict__ cnt, int N)
{
    int tid = blockIdx.x * 256 + threadIdx.x;
    if (tid < N + 16) cnt[tid] = 0;
    if (tid < N * 8) {
        int n = tid >> 3, s = tid & 7;
        const float* hp = &h[(size_t)n * DF + s * 8];
        float4 v0 = *(const float4*)hp;
        float4 v1 = *(const float4*)(hp + 4);
        ushort4 o0, o1;
        o0.x = bf16rne(v0.x); o0.y = bf16rne(v0.y); o0.z = bf16rne(v0.z); o0.w = bf16rne(v0.w);
        o1.x = bf16rne(v1.x); o1.y = bf16rne(v1.y); o1.z = bf16rne(v1.z); o1.w = bf16rne(v1.w);
        unsigned short* op = &hbs[(size_t)s * N * 8 + (size_t)n * 8];
        *(ushort4*)op = o0;
        *(ushort4*)(op + 4) = o1;
    }
}

// ---------------------------------------------------------------------------
// K2: dst-partitioned ELL fill (partition p = blockIdx&7 -> XCD heuristic;
// correctness never depends on the mapping). Partition's cnt slice (50 KB)
// and ELL slice (1.6 MB) stay L2-resident. Plain stores (r6: atomicExch
// regressed ~30us — atomic-pipe RMW serializes).
// ---------------------------------------------------------------------------
__device__ __forceinline__ void ell_push(
    int d, int s, int* cnt, int* ell, int* ovf, int* ovfcnt, int cap)
{
    int slot = atomicAdd(&cnt[d], 1);
    if (slot < ELLK) {
        ell[(size_t)d * ELLK + slot] = s;
    } else {
        int p = atomicAdd(ovfcnt, 1);
        if (p < cap) { ovf[2 * p] = d; ovf[2 * p + 1] = s; }
    }
}

__global__ __launch_bounds__(256) void fill_ell(
    const int* __restrict__ src, const int* __restrict__ dst,
    int* __restrict__ cnt, int* __restrict__ ell,
    int* __restrict__ ovf, int* __restrict__ ovfcnt, int ovfcap, int E, int N)
{
    int part = blockIdx.x & 7;
    int chunk = blockIdx.x >> 3;
    int nchunks = gridDim.x >> 3;
    int lo = (int)((long long)part * N / 8);
    int hi = (int)((long long)(part + 1) * N / 8);
    int seg = ((E + nchunks - 1) / nchunks + 3) & ~3;
    int e0 = chunk * seg;
    int e1 = e0 + seg; if (e1 > E) e1 = E;

    for (int i = e0 + threadIdx.x * 4; i < e1; i += 256 * 4) {
        if (i + 3 < e1) {
            int4 d = *(const int4*)&dst[i];
            int4 s = *(const int4*)&src[i];
            if (d.x >= lo && d.x < hi) ell_push(d.x, s.x, cnt, ell, ovf, ovfcnt, ovfcap);
            if (d.y >= lo && d.y < hi) ell_push(d.y, s.y, cnt, ell, ovf, ovfcnt, ovfcap);
            if (d.z >= lo && d.z < hi) ell_push(d.z, s.z, cnt, ell, ovf, ovfcnt, ovfcap);
            if (d.w >= lo && d.w < hi) ell_push(d.w, s.w, cnt, ell, ovf, ovfcnt, ovfcap);
        } else {
            for (int j = i; j < e1; ++j) {
                int d = dst[j];
                if (d >= lo && d < hi) ell_push(d, src[j], cnt, ell, ovf, ovfcnt, ovfcap);
            }
        }
    }
}

// ---------------------------------------------------------------------------
// K3: feature-sliced gather, v2. Slice = blockIdx&7 (XCD-resident 1.6 MB
// sub-table). Wave-iter covers 4 NODES: lane = ns*16 + nb*2 + fp
// (ns=node_sub 0..3, nb=neighbor_sub 0..7, fp=feat-quad 0..1).
// Each lane serially sums neighbors nb, nb+8, nb+16, nb+24: 4 independent
// id loads then 4 independent 8B gathers in flight (latency hidden), then
// ONE 3-level shfl_xor reduce over nb -> 12 bpermutes per 4 nodes = 3/node
// (r7 had 20/node: 16M DS ops = the 200us bottleneck).
// ---------------------------------------------------------------------------
__global__ __launch_bounds__(512) void gather_slice(
    const unsigned short* __restrict__ hbs, const int* __restrict__ cnt,
    const int* __restrict__ ell, unsigned short* __restrict__ csum, int N)
{
    int slice = blockIdx.x & 7;
    int wave = threadIdx.x >> 6, lane = threadIdx.x & 63;
    const int ns = lane >> 4;       // node sub 0..3
    const int q  = lane & 15;
    const int nb = q >> 1;          // neighbor sub 0..7
    const int fp = q & 1;           // feature-quad 0..1
    const unsigned short* tab = hbs + (size_t)slice * N * 8;
    unsigned short* cs = csum + (size_t)slice * N * 8;

    int gw = (blockIdx.x >> 3) * 8 + wave;
    int nw = (gridDim.x >> 3) * 8;

    for (int n0 = gw * 4; n0 < N; n0 += nw * 4) {
        int n = n0 + ns;
        bool valid = (n < N);
        int deg = valid ? cnt[n] : 0;
        int m = deg < ELLK ? deg : ELLK;
        const int* erow = &ell[(size_t)(valid ? n : 0) * ELLK];

        // 4 independent id loads (guarded), then 4 independent gathers
        int id0 = (nb      < m) ? erow[nb]      : -1;
        int id1 = (nb +  8 < m) ? erow[nb +  8] : -1;
        int id2 = (nb + 16 < m) ? erow[nb + 16] : -1;
        int id3 = (nb + 24 < m) ? erow[nb + 24] : -1;

        float4 a0 = make_float4(0.f, 0.f, 0.f, 0.f);
        float4 a1 = make_float4(0.f, 0.f, 0.f, 0.f);
        float4 a2 = make_float4(0.f, 0.f, 0.f, 0.f);
        float4 a3 = make_float4(0.f, 0.f, 0.f, 0.f);
        if (id0 >= 0) {
            ushort4 u = *(const ushort4*)&tab[(size_t)id0 * 8 + fp * 4];
            a0.x = b2f(u.x); a0.y = b2f(u.y); a0.z = b2f(u.z); a0.w = b2f(u.w);
        }
        if (id1 >= 0) {
            ushort4 u = *(const ushort4*)&tab[(size_t)id1 * 8 + fp * 4];
            a1.x = b2f(u.x); a1.y = b2f(u.y); a1.z = b2f(u.z); a1.w = b2f(u.w);
        }
        if (id2 >= 0) {
            ushort4 u = *(const ushort4*)&tab[(size_t)id2 * 8 + fp * 4];
            a2.x = b2f(u.x); a2.y = b2f(u.y); a2.z = b2f(u.z); a2.w = b2f(u.w);
        }
        if (id3 >= 0) {
            ushort4 u = *(const ushort4*)&tab[(size_t)id3 * 8 + fp * 4];
            a3.x = b2f(u.x); a3.y = b2f(u.y); a3.z = b2f(u.z); a3.w = b2f(u.w);
        }
        a0.x += a1.x + a2.x + a3.x;
        a0.y += a1.y + a2.y + a3.y;
        a0.z += a1.z + a2.z + a3.z;
        a0.w += a1.w + a2.w + a3.w;

        // reduce over nb (lane bits 1..3): 3 levels x 4 floats = 12 bpermutes
        #pragma unroll
        for (int msk = 2; msk <= 8; msk <<= 1) {
            a0.x += __shfl_xor(a0.x, msk);
            a0.y += __shfl_xor(a0.y, msk);
            a0.z += __shfl_xor(a0.z, msk);
            a0.w += __shfl_xor(a0.w, msk);
        }

        if (valid && nb == 0) {  // lanes ns*16 + {0,1} hold the full sums
            ushort4 o;
            o.x = bf16rne(a0.x); o.y = bf16rne(a0.y);
            o.z = bf16rne(a0.z); o.w = bf16rne(a0.w);
            *(ushort4*)&cs[(size_t)n * 8 + fp * 4] = o;  // bf16 partial SUM
        }
    }
}

// ---------------------------------------------------------------------------
// K4: streaming update (verified epilogue r1-r7). One wave per node; 8 waves
// share one LDS W copy; LDS-staged x, W-row dot, L2-normalize, relu,
// where(deg>0), residual.
// ---------------------------------------------------------------------------
__global__ __launch_bounds__(512, 4) void sage_update(
    const float* __restrict__ h, const float* __restrict__ W,
    const float* __restrict__ b, const int* __restrict__ cnt,
    const unsigned short* __restrict__ csum,
    const int* __restrict__ ovf, const int* __restrict__ ovfcnt,
    int ovfcap, float* __restrict__ out, int N)
{
    __shared__ float Wp[DF * WSTRIDE];
    __shared__ float bs[DF];
    __shared__ float xbuf[8][128];

    for (int i = threadIdx.x; i < DF * 128; i += 512) {
        int o = i >> 7, k = i & 127;
        Wp[o * WSTRIDE + k] = W[i];
    }
    if (threadIdx.x < DF) bs[threadIdx.x] = b[threadIdx.x];
    __syncthreads();

    const int wave = threadIdx.x >> 6;
    const int lane = threadIdx.x & 63;
    const int gw = blockIdx.x * 8 + wave;
    const int nw = gridDim.x * 8;
    float* xb = xbuf[wave];
    const float* wrow = &Wp[lane * WSTRIDE];
    const float bias = bs[lane];
    const size_t coff = (size_t)(lane >> 3) * N * 8 + (lane & 7);  // slice-major

    for (int n = gw; n < N; n += nw) {
        int deg = cnt[n];
        float hv = h[(size_t)n * DF + lane];
        float csv = b2f(csum[coff + (size_t)n * 8]);

        if (deg > ELLK) {  // overflow slow path, exact
            int oc = *ovfcnt; if (oc > ovfcap) oc = ovfcap;
            for (int t = 0; t < oc; ++t) {
                if (ovf[2 * t] == n) csv += h[(size_t)ovf[2 * t + 1] * DF + lane];
            }
        }

        float dg = (float)deg;
        float cv = csv / fmaxf(dg, 1.0f);

        xb[lane] = hv;
        xb[DF + lane] = cv;   // wave-synchronous LDS

        float y = bias;
        #pragma unroll
        for (int k = 0; k < 128; k += 4) {
            float4 xk = *(const float4*)&xb[k];
            float4 wk = *(const float4*)&wrow[k];
            y += xk.x * wk.x;
            y += xk.y * wk.y;
            y += xk.z * wk.z;
            y += xk.w * wk.w;
        }

        float ss = y * y;
        #pragma unroll
        for (int s = 1; s < 64; s <<= 1) ss += __shfl_xor(ss, s);

        float norm = sqrtf(ss);
        float nb2 = y / fmaxf(norm, 1e-12f);
        float nh = fmaxf(nb2, 0.0f);
        float hupd = (dg > 0.0f) ? nh : hv;
        out[(size_t)n * DF + lane] = hv + hupd;
    }
}

extern "C" void kernel_launch(void* const* d_in, const int* in_sizes, int n_in,
                              void* d_out, int out_size, void* d_ws, size_t ws_size,
                              hipStream_t stream) {
    const float* h   = (const float*)d_in[0];
    const float* W   = (const float*)d_in[1];
    const float* b   = (const float*)d_in[2];
    const int*   src = (const int*)d_in[3];
    const int*   dst = (const int*)d_in[4];
    float* out = (float*)d_out;

    const int N = in_sizes[0] / DF;
    const int E = in_sizes[3];

    // workspace carve (16B-aligned)
    int* cnt    = (int*)d_ws;
    int* ovfcnt = cnt + N;
    int* ell    = cnt + ((N + 31) & ~15);
    unsigned short* hbs  = (unsigned short*)(ell + (((size_t)N * ELLK + 15) & ~(size_t)15));
    unsigned short* csum = hbs + (((size_t)N * DF + 15) & ~(size_t)15);
    int* ovf    = (int*)(csum + (((size_t)N * DF + 15) & ~(size_t)15));
    size_t used = (size_t)((char*)ovf - (char*)d_ws);
    int ovfcap  = (ws_size > used + 64) ? (int)((ws_size - used) / 8 - 4) : 0;

    // K1: bf16 slice-major conversion + counter zeroing
    conv_zero<<<(N * 8 + 255) / 256, 256, 0, stream>>>(h, hbs, cnt, N);

    // K2: dst-partitioned ELL build
    fill_ell<<<1024, 256, 0, stream>>>(src, dst, cnt, ell, ovf, ovfcnt, ovfcap, E, N);

    // K3: feature-sliced gather v2 (4 nodes/wave-iter, 3 shfl/node)
    gather_slice<<<2048, 512, 0, stream>>>(hbs, cnt, ell, csum, N);

    // K4: streaming update
    sage_update<<<1024, 512, 0, stream>>>(h, W, b, cnt, csum, ovf, ovfcnt, ovfcap, out, N);
}